// Round 16
// baseline (97.815 us; speedup 1.0000x reference)
//
#include <hip/hip_runtime.h>
#include <math.h>

#define N_    16
#define C_    256
#define H_    56
#define W_    56
#define HW_   3136          // H_*W_
#define NPIX  50176         // N_*HW_
#define OUTC  512
#define SPAN_ 2304          // C_*9
#define BLKPX 256           // conv block pixel tile
#define HBYTES 24576        // one halo buffer: 384 slots * 64 B
#define PXB   128           // prep pixel tile
#define NPQ   (4 * NPIX / PXB) // 1568 prep blocks (4 channel-quarters per tile)
#define NVB   (NPIX / 256)  // 196 vote pixel blocks

typedef unsigned short u16;
typedef unsigned int   u32;
typedef __attribute__((ext_vector_type(8))) short bf16x8;
typedef __attribute__((ext_vector_type(8))) unsigned short u16x8;
typedef __attribute__((ext_vector_type(4))) unsigned short u16x4;
typedef __attribute__((ext_vector_type(4))) float f32x4;

__device__ __forceinline__ u16 f2bf(float v) {
    u32 x = __float_as_uint(v);
    u32 r = (x + 0x7fffu + ((x >> 16) & 1u)) >> 16;   // RNE
    return (u16)r;
}

__device__ __forceinline__ int bucketf(float v, float b) {
    int idx = (int)floorf((v + b) / 2.5f);
    int r = idx % 8;
    return r < 0 ? -r : r;
}

// ---- Kernel 1: prep2q -- NCHW f32 -> NHWC bf16 + tap-map QUARTER partials ---
// grid = 1568: block b -> px tile (b>>2)*128, channel quarter (b&3)*64..+63.
// Verified prep2h structure (16-deep double-buffered loads, LDS transpose for
// coalesced xp stores), one 64-channel phase. Partials gp[q][kk][px] and
// s2 gp[36*NPIX + q*NPIX + px] live in the d_out scratch window (lifetime-
// disjoint from conv's writes). 6.1 blocks/CU -> ~3 waves/SIMD.
__global__ __launch_bounds__(128) void prep2q(const float* __restrict__ x,
                                              const float* __restrict__ ah,
                                              u16* __restrict__ xp,
                                              float* __restrict__ gp) {
    int t = threadIdx.x;
    const int quarter = blockIdx.x & 3;
    const int tile = blockIdx.x >> 2;
    const int coff = quarter * 64;        // channel base for this block

    __shared__ float aL[64 * 9];          // 2304 B (this quarter's taps)
    __shared__ u16 tl[PXB][68];           // 17408 B
    for (int j = t; j < 64 * 9; j += 128) aL[j] = ah[coff * 9 + j];

    const int px = tile * PXB + t;
    const int img = px / HW_;
    const size_t xbase = (size_t)img * C_ * HW_ + (px - img * HW_);

    float pg[9];
#pragma unroll
    for (int kk = 0; kk < 9; ++kk) pg[kk] = 0.f;
    float ps = 0.f;
    __syncthreads();

    float R[16], Rn[16];
#pragma unroll
    for (int i = 0; i < 16; ++i)
        R[i] = x[xbase + (size_t)(coff + i) * HW_];
#pragma unroll
    for (int sub = 0; sub < 4; ++sub) {
        if (sub < 3) {
#pragma unroll
            for (int i = 0; i < 16; ++i)
                Rn[i] = x[xbase + (size_t)(coff + (sub + 1) * 16 + i) * HW_];
        }
#pragma unroll
        for (int i = 0; i < 16; ++i) {
            int cl = sub * 16 + i;               // local channel 0..63
            float v = R[i];
            const float* ac = &aL[cl * 9];
#pragma unroll
            for (int kk = 0; kk < 9; ++kk) pg[kk] += ac[kk] * v;
            ps += v * v;
            tl[t][cl] = f2bf(v);
        }
        if (sub < 3) {
#pragma unroll
            for (int i = 0; i < 16; ++i) R[i] = Rn[i];
        }
    }
    __syncthreads();
    // xp write: 128 px x 64 ch slab, coalesced 16-B chunks (8 passes)
    const int oct = t & 7;
#pragma unroll
    for (int pass = 0; pass < 8; ++pass) {
        int pxl = pass * 16 + (t >> 3);
        u16x8 v8 = *(const u16x8*)&tl[pxl][oct * 8];
        *(u16x8*)&xp[((size_t)(tile * PXB + pxl)) * C_ + coff + oct * 8] = v8;
    }

    // partial outputs
    float* gq = gp + (size_t)quarter * 9 * NPIX;
#pragma unroll
    for (int kk = 0; kk < 9; ++kk) gq[(size_t)kk * NPIX + px] = pg[kk];
    gp[(size_t)36 * NPIX + (size_t)quarter * NPIX + px] = ps;
}

// ---- Kernel B2 (+A): vote -> histogram; 128 tail blocks do kbucket ----------
__global__ __launch_bounds__(256) void vote_kernel(const float* __restrict__ gp,
                                                   const float* __restrict__ ah,
                                                   const float* __restrict__ bh,
                                                   const float* __restrict__ kern,
                                                   int* __restrict__ counts,
                                                   int* __restrict__ kbuck) {
    int kb = blockIdx.x - NVB;
    if (kb >= 0) {
        int wv = threadIdx.x >> 6, lane = threadIdx.x & 63;
        int oc = kb * 4 + wv;
        const float* kr = kern + (size_t)oc * SPAN_;
        float dot = 0.f, ss = 0.f;
#pragma unroll
        for (int i = 0; i < 9; ++i) {
            float4 kv = *(const float4*)(kr + i * 256 + lane * 4);
            float4 av = *(const float4*)(ah + i * 256 + lane * 4);
            dot += kv.x * av.x + kv.y * av.y + kv.z * av.z + kv.w * av.w;
            ss  += kv.x * kv.x + kv.y * kv.y + kv.z * kv.z + kv.w * kv.w;
        }
#pragma unroll
        for (int off = 32; off; off >>= 1) {
            dot += __shfl_xor(dot, off);
            ss  += __shfl_xor(ss, off);
        }
        if (lane == 0) {
            float n2 = ss;            // ||k||^2
            float n4 = n2 * n2;
            float n8 = n4 * n4;
            float v = dot + n2 * ah[SPAN_] + n4 * ah[SPAN_ + 1] +
                      n8 * ah[SPAN_ + 2];
            kbuck[oc] = bucketf(v, bh[0]);
        }
        return;
    }

    __shared__ int hist[8];
    if (threadIdx.x < 8) hist[threadIdx.x] = 0;
    __syncthreads();
    int q = blockIdx.x * 256 + threadIdx.x;
    int n = q / HW_;
    int p = q - n * HW_;
    int h = p / W_;
    int w = p - h * W_;
    const float* s2q = gp + (size_t)36 * NPIX;
    float dot = 0.f, ss = 0.f;
#pragma unroll
    for (int kk = 0; kk < 9; ++kk) {
        int dh = kk / 3 - 1, dw = kk % 3 - 1;
        int hh = h + dh, ww = w + dw;
        if (hh >= 0 && hh < H_ && ww >= 0 && ww < W_) {
            int idx = n * HW_ + hh * W_ + ww;
            dot += gp[(size_t)kk * NPIX + idx] +
                   gp[(size_t)(9 + kk) * NPIX + idx] +
                   gp[(size_t)(18 + kk) * NPIX + idx] +
                   gp[(size_t)(27 + kk) * NPIX + idx];
            ss  += s2q[idx] + s2q[(size_t)NPIX + idx] +
                   s2q[(size_t)2 * NPIX + idx] + s2q[(size_t)3 * NPIX + idx];
        }
    }
    float qext = 0.5f * (ah[SPAN_] + ah[SPAN_ + 1] + ah[SPAN_ + 2]);
    float v = dot / sqrtf(ss) + qext;
    int b = bucketf(v, bh[0]);
    atomicAdd(&hist[b], 1);
    __syncthreads();
    if (threadIdx.x < 8) atomicAdd(&counts[threadIdx.x], hist[threadIdx.x]);
}

// ---- Kernel P2: self-selecting weight fragmentation -------------------------
__global__ __launch_bounds__(256) void prep_w(const float* __restrict__ kern,
                                              const int* __restrict__ kbuck,
                                              const int* __restrict__ counts,
                                              const int* __restrict__ mode,
                                              float* __restrict__ out,
                                              u16* __restrict__ wfrag,
                                              int nfB, int oc_total) {
    __shared__ int sc[256];
    __shared__ int rowsL[512];
    int t = threadIdx.x;
    int best = 0, bc = counts[0];
#pragma unroll
    for (int i = 1; i < 8; ++i) {
        int c = counts[i];
        if (c > bc) { bc = c; best = i; }   // first max wins
    }
    int f0 = (kbuck[t] == best) ? 1 : 0;
    int f1 = (kbuck[t + 256] == best) ? 1 : 0;
    sc[t] = f0 | (f1 << 16);
    __syncthreads();
    for (int off = 1; off < 256; off <<= 1) {
        int add = (t >= off) ? sc[t - off] : 0;
        __syncthreads();
        sc[t] += add;
        __syncthreads();
    }
    int tot = sc[255];
    int t0  = tot & 0xffff;
    int cnt = t0 + (tot >> 16);
    int pos0 = (sc[t] & 0xffff) - f0;
    int pos1 = t0 + (sc[t] >> 16) - f1;
    rowsL[t] = 0; rowsL[t + 256] = 0;
    __syncthreads();
    if (cnt == 0) { rowsL[t] = t; rowsL[t + 256] = t + 256; }
    else {
        if (f0) rowsL[pos0] = t;
        if (f1) rowsL[pos1] = t + 256;
    }
    __syncthreads();
    int ocEff = (cnt == 0) ? OUTC : cnt;
    float scale = (mode[0] && cnt > 0) ? 512.0f / (float)cnt : 1.0f;

    if (blockIdx.x == 0) {                       // rows output (read as f32)
        float* rout = out + (size_t)N_ * oc_total * HW_;
        int nw = ocEff < oc_total ? ocEff : oc_total;
        if (cnt == 0) {
            if (t < nw) rout[t] = (float)t;
            if (t + 256 < nw) rout[t + 256] = (float)(t + 256);
        } else {
            if (f0 && pos0 < nw) rout[pos0] = (float)t;
            if (f1 && pos1 < nw) rout[pos1] = (float)(t + 256);
        }
    }

    // fragmentation: wfrag elem offset ((s*nfB + g)*64 + lane)*8, K = kk*256+c
    int e = blockIdx.x * 256 + t;
    int lane = e & 63;
    int t2 = e >> 6;
    int g = t2 % nfB;
    int s = t2 / nfB;                    // 0..71
    int kk = s >> 3;
    int cb = s & 7;
    int q = lane >> 4;
    int mcol = lane & 15;
    int oc_i = g * 16 + mcol;
    bool valid = oc_i < ocEff;
    int row = valid ? rowsL[oc_i] : 0;
    const float* kr = kern + (size_t)row * SPAN_;
    u16 w8[8];
#pragma unroll
    for (int j = 0; j < 8; ++j) {
        int c = cb * 32 + q * 8 + j;
        float v = valid ? kr[c * 9 + kk] * scale : 0.f;
        w8[j] = f2bf(v);
    }
    u16* dst = wfrag + ((size_t)((s * nfB + g) * 64 + lane)) * 8;
#pragma unroll
    for (int j = 0; j < 8; ++j) dst[j] = w8[j];
}

// ---- Kernel D: MFMA implicit-GEMM conv (round-9 version, measured 49.5-50.3) -
// 4 waves/block, block tile 256 px x 48 oc. A staged via global_load_lds into a
// double-buffered quarter-XOR-swizzled LDS halo (1 barrier per 32-ch step,
// fully unrolled -> ds_read immediate offsets); invalid taps masked by cndmask;
// B register-pipelined one kk ahead, continuous across the cb seam.
__global__ __launch_bounds__(256, 2) void conv_mfma(const u16* __restrict__ xp,
                                                    const u16* __restrict__ wfrag,
                                                    float* __restrict__ out,
                                                    int nfB, int oc_total, int nby) {
    __shared__ char halo[2 * HBYTES];              // 49152 B

    // XCD swizzle: oc-sibling blocks co-located on one XCD; 196 bx = 24*8 + 4.
    int flat = blockIdx.x;
    int bx, by;
    int full = 192 * nby;
    if (flat < full) {
        int gsz = 8 * nby;
        int gi = flat / gsz;
        int tr = flat - gi * gsz;
        by = tr >> 3;
        bx = gi * 8 + (tr & 7);
    } else {
        int tr = flat - full;
        by = tr >> 2;
        bx = 192 + (tr & 3);
    }

    const int t = threadIdx.x;
    const int lane = t & 63;
    const int wv = t >> 6;                         // 0..3
    const int pb = bx * BLKPX;
    const int fb = by * 3;
    const int lane15 = lane & 15;
    const int laneq  = lane >> 4;

    // per-fragment validity masks (bit kk) + swizzled LDS read bases per dw.
    // base holds -3584 bias so the ds_read immediate (dh+1)*3584 stays >= 0.
    u32 valMask[4];
    int aB[4][3];
#pragma unroll
    for (int f = 0; f < 4; ++f) {
        int p = pb + wv * 64 + f * 16 + lane15;
        int img = p / HW_;
        int rp = p - img * HW_;
        int h = rp / W_;
        int w = rp - h * W_;
        u32 m = 0;
#pragma unroll
        for (int kk = 0; kk < 9; ++kk) {
            int dh = kk / 3 - 1, dw = kk % 3 - 1;
            int hh = h + dh, ww = w + dw;
            if (hh >= 0 && hh < H_ && ww >= 0 && ww < W_) m |= (1u << kk);
        }
        valMask[f] = m;
#pragma unroll
        for (int j = 0; j < 3; ++j) {               // dw = j-1
            int sn = 57 + wv * 64 + f * 16 + lane15 + (j - 1);
            aB[f][j] = sn * 64 + ((laneq ^ ((sn >> 1) & 3)) << 4) - 3584;
        }
    }

    f32x4 acc[4][3];
#pragma unroll
    for (int f = 0; f < 4; ++f)
#pragma unroll
        for (int gg = 0; gg < 3; ++gg) acc[f][gg] = (f32x4){0.f, 0.f, 0.f, 0.f};
    const bf16x8 zf = {0, 0, 0, 0, 0, 0, 0, 0};

    // staging: 6 global_load_lds_dwordx4/thread; LDS dest linear t*16;
    // global source quarter pre-swizzled: q' = (t&3) ^ ((t>>3)&3)
    const char* xpb = (const char*)xp;
    const int q4 = (((t & 3) ^ ((t >> 3) & 3)) << 4);
    int gpx[6];
#pragma unroll
    for (int r = 0; r < 6; ++r) {
        int p = pb - 57 + r * 64 + (t >> 2);
        gpx[r] = p < 0 ? 0 : (p >= NPIX ? NPIX - 1 : p);
    }

    // prologue: stage cb=0 into buf 0, load B(cb=0,kk=0)
#pragma unroll
    for (int r = 0; r < 6; ++r)
        __builtin_amdgcn_global_load_lds(
            (const __attribute__((address_space(1))) unsigned int*)
                (xpb + (size_t)gpx[r] * 512 + q4),
            (__attribute__((address_space(3))) unsigned int*)&halo[r * 4096 + t * 16],
            16, 0, 0);

    const size_t cbStride = (size_t)nfB * 512;
    const size_t kkStride = cbStride * 8;
    const u16* wl = wfrag + (size_t)fb * 512 + (size_t)lane * 8;
    bf16x8 bW[3], bWn[3];
#define LOADB(dst, cb_, kk_) do {                                               \
    const u16* _wp = wl + (size_t)(kk_) * kkStride + (size_t)(cb_) * cbStride;  \
    _Pragma("unroll")                                                           \
    for (int _g = 0; _g < 3; ++_g)                                              \
        dst[_g] = *(const bf16x8*)(_wp + (size_t)_g * 512);                     \
} while (0)

    LOADB(bW, 0, 0);

#pragma unroll
    for (int cb = 0; cb < 8; ++cb) {
        __syncthreads();                           // buf[cb&1] ready

        if (cb < 7) {                              // stage next cb, other buf
            const int nb = ((cb + 1) & 1) * HBYTES;
#pragma unroll
            for (int r = 0; r < 6; ++r)
                __builtin_amdgcn_global_load_lds(
                    (const __attribute__((address_space(1))) unsigned int*)
                        (xpb + (size_t)gpx[r] * 512 + (cb + 1) * 64 + q4),
                    (__attribute__((address_space(3))) unsigned int*)
                        &halo[nb + r * 4096 + t * 16],
                    16, 0, 0);
        }

#pragma unroll
        for (int kk = 0; kk < 9; ++kk) {
            // B prefetch distance 1, continuous across the cb seam
            if (kk < 8)       LOADB(bWn, cb, kk + 1);
            else if (cb < 7)  LOADB(bWn, cb + 1, 0);

            const int dh = kk / 3 - 1;
            const int j  = kk % 3;                 // dw + 1
            const int IMM = (cb & 1) * HBYTES + (dh + 1) * 3584;  // compile-time
            bf16x8 aX[4];
#pragma unroll
            for (int f = 0; f < 4; ++f) {
                bf16x8 a = *(const bf16x8*)&halo[aB[f][j] + IMM];
                aX[f] = ((valMask[f] >> kk) & 1) ? a : zf;
            }
#pragma unroll
            for (int gg = 0; gg < 3; ++gg)
#pragma unroll
                for (int f = 0; f < 4; ++f)
                    acc[f][gg] = __builtin_amdgcn_mfma_f32_16x16x32_bf16(
                        aX[f], bW[gg], acc[f][gg], 0, 0, 0);
            if (kk < 8 || cb < 7) {
#pragma unroll
                for (int gg = 0; gg < 3; ++gg) bW[gg] = bWn[gg];
            }
        }
    }
#undef LOADB

    // epilogue: D row (pixel) = (lane>>4)*4 + r, col (oc) = lane&15
#pragma unroll
    for (int f = 0; f < 4; ++f) {
        int p0 = pb + wv * 64 + f * 16 + laneq * 4;
        int img0 = p0 / HW_;
        int hw0 = p0 - img0 * HW_;
#pragma unroll
        for (int gg = 0; gg < 3; ++gg) {
            int oc = (fb + gg) * 16 + lane15;
            if (oc < oc_total) {
                float* op = out + ((size_t)img0 * oc_total + oc) * HW_ + hw0;
                *(f32x4*)op = acc[f][gg];
            }
        }
    }
}

extern "C" void kernel_launch(void* const* d_in, const int* in_sizes, int n_in,
                              void* d_out, int out_size, void* d_ws, size_t ws_size,
                              hipStream_t stream) {
    const float* x    = (const float*)d_in[0];
    const float* kern = (const float*)d_in[1];
    const float* ah   = (const float*)d_in[2];
    const float* bh   = (const float*)d_in[3];
    const int*   mode = (const int*)d_in[4];
    float* out = (float*)d_out;

    // oc is data-dependent but recoverable from out_size: oc*(16*3136+1)
    int oc_total = (out_size % (N_ * HW_ + 1) == 0) ? out_size / (N_ * HW_ + 1)
                                                    : OUTC;
    int nfTot = (oc_total + 15) / 16;
    int nby   = (nfTot + 2) / 3;             // 3 fragments (48 oc) per block
    int nfB   = nby * 3;

    // workspace: xp + wfrag + flags (~28.4 MB, under proven envelope).
    u16*   xp     = (u16*)d_ws;                                  // NPIX*C_ u16
    u16*   wfrag  = xp + (size_t)NPIX * C_;                      // 72*36*64*8
    int*   counts = (int*)(wfrag + (size_t)72 * 36 * 64 * 8);    // 8
    int*   kbuck  = counts + 8;                                  // 512

    // Partials scratch lives in d_out (40*NPIX f32 = 8.03 MB), lifetime-
    // disjoint from conv's output writes (conv runs last and overwrites).
    // out main section = 16*oc_total*3136 f32 >= 28.9 MB >> 8.03 MB.
    float* gp = out;

    hipMemsetAsync(counts, 0, 8 * sizeof(int), stream);

    prep2q<<<NPQ, 128, 0, stream>>>(x, ah, xp, gp);
    vote_kernel<<<NVB + 128, 256, 0, stream>>>(gp, ah, bh, kern, counts,
                                               kbuck);
    prep_w<<<18 * nfB, 256, 0, stream>>>(kern, kbuck, counts, mode, out, wfrag,
                                         nfB, oc_total);
    conv_mfma<<<(NPIX / BLKPX) * nby, 256, 0, stream>>>(xp, wfrag, out, nfB,
                                                        oc_total, nby);
}

// Round 17
// 90.964 us; speedup vs baseline: 1.0753x; 1.0753x over previous
//
#include <hip/hip_runtime.h>
#include <math.h>

#define N_    16
#define C_    256
#define H_    56
#define W_    56
#define HW_   3136          // H_*W_
#define NPIX  50176         // N_*HW_
#define OUTC  512
#define SPAN_ 2304          // C_*9
#define BLKPX 256           // conv block pixel tile
#define HBYTES 24576        // one halo buffer: 384 slots * 64 B
#define PXB   128           // prep2 pixel tile
#define NPB2  (2 * NPIX / PXB) // 784 prep2 blocks (2 channel-halves per tile)
#define NVB   (NPIX / 256)  // 196 vote pixel blocks

typedef unsigned short u16;
typedef unsigned int   u32;
typedef __attribute__((ext_vector_type(8))) short bf16x8;
typedef __attribute__((ext_vector_type(8))) unsigned short u16x8;
typedef __attribute__((ext_vector_type(4))) unsigned short u16x4;
typedef __attribute__((ext_vector_type(4))) float f32x4;

__device__ __forceinline__ u16 f2bf(float v) {
    u32 x = __float_as_uint(v);
    u32 r = (x + 0x7fffu + ((x >> 16) & 1u)) >> 16;   // RNE
    return (u16)r;
}

__device__ __forceinline__ int bucketf(float v, float b) {
    int idx = (int)floorf((v + b) / 2.5f);
    int r = idx % 8;
    return r < 0 ? -r : r;
}

// ---- Kernel 1: prep2h -- NCHW f32 -> NHWC bf16 + tap-map PARTIALS -----------
// (round-15 version, verified) grid = 784: block b -> px tile (b>>1)*128,
// channel half (b&1)*128..+127.
__global__ __launch_bounds__(128) void prep2h(const float* __restrict__ x,
                                              const float* __restrict__ ah,
                                              u16* __restrict__ xp,
                                              float* __restrict__ gp,
                                              float* __restrict__ s2p) {
    int t = threadIdx.x;
    const int half = blockIdx.x & 1;
    const int tile = blockIdx.x >> 1;
    const int coff = half * 128;          // channel base for this block

    __shared__ float aL[128 * 9];         // 4608 B (this half's taps)
    __shared__ u16 tl[PXB][68];           // 17408 B
    for (int j = t; j < 128 * 9; j += 128) aL[j] = ah[coff * 9 + j];

    const int px = tile * PXB + t;
    const int img = px / HW_;
    const size_t xbase = (size_t)img * C_ * HW_ + (px - img * HW_);

    float pg[9];
#pragma unroll
    for (int kk = 0; kk < 9; ++kk) pg[kk] = 0.f;
    float ps = 0.f;
    __syncthreads();

    for (int ph = 0; ph < 2; ++ph) {      // two 64-channel slabs
        const int c0 = coff + ph * 64;
        float R[16], Rn[16];
#pragma unroll
        for (int i = 0; i < 16; ++i)
            R[i] = x[xbase + (size_t)(c0 + i) * HW_];
#pragma unroll
        for (int sub = 0; sub < 4; ++sub) {
            if (sub < 3) {
#pragma unroll
                for (int i = 0; i < 16; ++i)
                    Rn[i] = x[xbase + (size_t)(c0 + (sub + 1) * 16 + i) * HW_];
            }
#pragma unroll
            for (int i = 0; i < 16; ++i) {
                int cl = ph * 64 + sub * 16 + i;     // local channel 0..127
                float v = R[i];
                const float* ac = &aL[cl * 9];
#pragma unroll
                for (int kk = 0; kk < 9; ++kk) pg[kk] += ac[kk] * v;
                ps += v * v;
                tl[t][sub * 16 + i] = f2bf(v);
            }
            if (sub < 3) {
#pragma unroll
                for (int i = 0; i < 16; ++i) R[i] = Rn[i];
            }
        }
        __syncthreads();
        const int oct = t & 7;
#pragma unroll
        for (int pass = 0; pass < 8; ++pass) {
            int pxl = pass * 16 + (t >> 3);
            u16x8 v8 = *(const u16x8*)&tl[pxl][oct * 8];
            *(u16x8*)&xp[((size_t)(tile * PXB + pxl)) * C_ +
                         c0 + oct * 8] = v8;
        }
        __syncthreads();
    }

    // partial outputs: gp[half][kk][px], s2p[half][px]
    float* gh = gp + (size_t)half * 9 * NPIX;
#pragma unroll
    for (int kk = 0; kk < 9; ++kk) gh[(size_t)kk * NPIX + px] = pg[kk];
    s2p[(size_t)half * NPIX + px] = ps;
}

// ---- Kernel B2 (+A): vote -> histogram; 128 tail blocks do kbucket ----------
__global__ __launch_bounds__(256) void vote_kernel(const float* __restrict__ gp,
                                                   const float* __restrict__ s2p,
                                                   const float* __restrict__ ah,
                                                   const float* __restrict__ bh,
                                                   const float* __restrict__ kern,
                                                   int* __restrict__ counts,
                                                   int* __restrict__ kbuck) {
    int kb = blockIdx.x - NVB;
    if (kb >= 0) {
        int wv = threadIdx.x >> 6, lane = threadIdx.x & 63;
        int oc = kb * 4 + wv;
        const float* kr = kern + (size_t)oc * SPAN_;
        float dot = 0.f, ss = 0.f;
#pragma unroll
        for (int i = 0; i < 9; ++i) {
            float4 kv = *(const float4*)(kr + i * 256 + lane * 4);
            float4 av = *(const float4*)(ah + i * 256 + lane * 4);
            dot += kv.x * av.x + kv.y * av.y + kv.z * av.z + kv.w * av.w;
            ss  += kv.x * kv.x + kv.y * kv.y + kv.z * kv.z + kv.w * kv.w;
        }
#pragma unroll
        for (int off = 32; off; off >>= 1) {
            dot += __shfl_xor(dot, off);
            ss  += __shfl_xor(ss, off);
        }
        if (lane == 0) {
            float n2 = ss;            // ||k||^2
            float n4 = n2 * n2;
            float n8 = n4 * n4;
            float v = dot + n2 * ah[SPAN_] + n4 * ah[SPAN_ + 1] +
                      n8 * ah[SPAN_ + 2];
            kbuck[oc] = bucketf(v, bh[0]);
        }
        return;
    }

    __shared__ int hist[8];
    if (threadIdx.x < 8) hist[threadIdx.x] = 0;
    __syncthreads();
    int q = blockIdx.x * 256 + threadIdx.x;
    int n = q / HW_;
    int p = q - n * HW_;
    int h = p / W_;
    int w = p - h * W_;
    const float* g0 = gp;
    const float* g1 = gp + (size_t)9 * NPIX;
    float dot = 0.f, ss = 0.f;
#pragma unroll
    for (int kk = 0; kk < 9; ++kk) {
        int dh = kk / 3 - 1, dw = kk % 3 - 1;
        int hh = h + dh, ww = w + dw;
        if (hh >= 0 && hh < H_ && ww >= 0 && ww < W_) {
            int idx = n * HW_ + hh * W_ + ww;
            dot += g0[(size_t)kk * NPIX + idx] + g1[(size_t)kk * NPIX + idx];
            ss  += s2p[idx] + s2p[(size_t)NPIX + idx];
        }
    }
    float qext = 0.5f * (ah[SPAN_] + ah[SPAN_ + 1] + ah[SPAN_ + 2]);
    float v = dot / sqrtf(ss) + qext;
    int b = bucketf(v, bh[0]);
    atomicAdd(&hist[b], 1);
    __syncthreads();
    if (threadIdx.x < 8) atomicAdd(&counts[threadIdx.x], hist[threadIdx.x]);
}

// ---- Kernel P2: self-selecting weight fragmentation -------------------------
__global__ __launch_bounds__(256) void prep_w(const float* __restrict__ kern,
                                              const int* __restrict__ kbuck,
                                              const int* __restrict__ counts,
                                              const int* __restrict__ mode,
                                              float* __restrict__ out,
                                              u16* __restrict__ wfrag,
                                              int nfB, int oc_total) {
    __shared__ int sc[256];
    __shared__ int rowsL[512];
    int t = threadIdx.x;
    int best = 0, bc = counts[0];
#pragma unroll
    for (int i = 1; i < 8; ++i) {
        int c = counts[i];
        if (c > bc) { bc = c; best = i; }   // first max wins
    }
    int f0 = (kbuck[t] == best) ? 1 : 0;
    int f1 = (kbuck[t + 256] == best) ? 1 : 0;
    sc[t] = f0 | (f1 << 16);
    __syncthreads();
    for (int off = 1; off < 256; off <<= 1) {
        int add = (t >= off) ? sc[t - off] : 0;
        __syncthreads();
        sc[t] += add;
        __syncthreads();
    }
    int tot = sc[255];
    int t0  = tot & 0xffff;
    int cnt = t0 + (tot >> 16);
    int pos0 = (sc[t] & 0xffff) - f0;
    int pos1 = t0 + (sc[t] >> 16) - f1;
    rowsL[t] = 0; rowsL[t + 256] = 0;
    __syncthreads();
    if (cnt == 0) { rowsL[t] = t; rowsL[t + 256] = t + 256; }
    else {
        if (f0) rowsL[pos0] = t;
        if (f1) rowsL[pos1] = t + 256;
    }
    __syncthreads();
    int ocEff = (cnt == 0) ? OUTC : cnt;
    float scale = (mode[0] && cnt > 0) ? 512.0f / (float)cnt : 1.0f;

    if (blockIdx.x == 0) {                       // rows output (read as f32)
        float* rout = out + (size_t)N_ * oc_total * HW_;
        int nw = ocEff < oc_total ? ocEff : oc_total;
        if (cnt == 0) {
            if (t < nw) rout[t] = (float)t;
            if (t + 256 < nw) rout[t + 256] = (float)(t + 256);
        } else {
            if (f0 && pos0 < nw) rout[pos0] = (float)t;
            if (f1 && pos1 < nw) rout[pos1] = (float)(t + 256);
        }
    }

    // fragmentation: wfrag elem offset ((s*nfB + g)*64 + lane)*8, K = kk*256+c
    int e = blockIdx.x * 256 + t;
    int lane = e & 63;
    int t2 = e >> 6;
    int g = t2 % nfB;
    int s = t2 / nfB;                    // 0..71
    int kk = s >> 3;
    int cb = s & 7;
    int q = lane >> 4;
    int mcol = lane & 15;
    int oc_i = g * 16 + mcol;
    bool valid = oc_i < ocEff;
    int row = valid ? rowsL[oc_i] : 0;
    const float* kr = kern + (size_t)row * SPAN_;
    u16 w8[8];
#pragma unroll
    for (int j = 0; j < 8; ++j) {
        int c = cb * 32 + q * 8 + j;
        float v = valid ? kr[c * 9 + kk] * scale : 0.f;
        w8[j] = f2bf(v);
    }
    u16* dst = wfrag + ((size_t)((s * nfB + g) * 64 + lane)) * 8;
#pragma unroll
    for (int j = 0; j < 8; ++j) dst[j] = w8[j];
}

// ---- Kernel D: MFMA implicit-GEMM conv --------------------------------------
// Round-9 base (measured 49.5-50.3 three times) with ONE isolated change:
// B register ring extended to prefetch distance 2 (static 3-slot, fully
// unrolled, continuous across the cb seam). Everything else untouched.
__global__ __launch_bounds__(256, 2) void conv_mfma(const u16* __restrict__ xp,
                                                    const u16* __restrict__ wfrag,
                                                    float* __restrict__ out,
                                                    int nfB, int oc_total, int nby) {
    __shared__ char halo[2 * HBYTES];              // 49152 B

    // XCD swizzle: oc-sibling blocks co-located on one XCD; 196 bx = 24*8 + 4.
    int flat = blockIdx.x;
    int bx, by;
    int full = 192 * nby;
    if (flat < full) {
        int gsz = 8 * nby;
        int gi = flat / gsz;
        int tr = flat - gi * gsz;
        by = tr >> 3;
        bx = gi * 8 + (tr & 7);
    } else {
        int tr = flat - full;
        by = tr >> 2;
        bx = 192 + (tr & 3);
    }

    const int t = threadIdx.x;
    const int lane = t & 63;
    const int wv = t >> 6;                         // 0..3
    const int pb = bx * BLKPX;
    const int fb = by * 3;
    const int lane15 = lane & 15;
    const int laneq  = lane >> 4;

    // per-fragment validity masks (bit kk) + swizzled LDS read bases per dw.
    // base holds -3584 bias so the ds_read immediate (dh+1)*3584 stays >= 0.
    u32 valMask[4];
    int aB[4][3];
#pragma unroll
    for (int f = 0; f < 4; ++f) {
        int p = pb + wv * 64 + f * 16 + lane15;
        int img = p / HW_;
        int rp = p - img * HW_;
        int h = rp / W_;
        int w = rp - h * W_;
        u32 m = 0;
#pragma unroll
        for (int kk = 0; kk < 9; ++kk) {
            int dh = kk / 3 - 1, dw = kk % 3 - 1;
            int hh = h + dh, ww = w + dw;
            if (hh >= 0 && hh < H_ && ww >= 0 && ww < W_) m |= (1u << kk);
        }
        valMask[f] = m;
#pragma unroll
        for (int j = 0; j < 3; ++j) {               // dw = j-1
            int sn = 57 + wv * 64 + f * 16 + lane15 + (j - 1);
            aB[f][j] = sn * 64 + ((laneq ^ ((sn >> 1) & 3)) << 4) - 3584;
        }
    }

    f32x4 acc[4][3];
#pragma unroll
    for (int f = 0; f < 4; ++f)
#pragma unroll
        for (int gg = 0; gg < 3; ++gg) acc[f][gg] = (f32x4){0.f, 0.f, 0.f, 0.f};
    const bf16x8 zf = {0, 0, 0, 0, 0, 0, 0, 0};

    // staging: 6 global_load_lds_dwordx4/thread; LDS dest linear t*16;
    // global source quarter pre-swizzled: q' = (t&3) ^ ((t>>3)&3)
    const char* xpb = (const char*)xp;
    const int q4 = (((t & 3) ^ ((t >> 3) & 3)) << 4);
    int gpx[6];
#pragma unroll
    for (int r = 0; r < 6; ++r) {
        int p = pb - 57 + r * 64 + (t >> 2);
        gpx[r] = p < 0 ? 0 : (p >= NPIX ? NPIX - 1 : p);
    }

    // prologue: stage cb=0 into buf 0
#pragma unroll
    for (int r = 0; r < 6; ++r)
        __builtin_amdgcn_global_load_lds(
            (const __attribute__((address_space(1))) unsigned int*)
                (xpb + (size_t)gpx[r] * 512 + q4),
            (__attribute__((address_space(3))) unsigned int*)&halo[r * 4096 + t * 16],
            16, 0, 0);

    const size_t cbStride = (size_t)nfB * 512;
    const size_t kkStride = cbStride * 8;
    const u16* wl = wfrag + (size_t)fb * 512 + (size_t)lane * 8;
    bf16x8 bB[3][3];                               // 3-slot ring, distance 2
#define LOADB(slot, cb_, kk_) do {                                              \
    const u16* _wp = wl + (size_t)(kk_) * kkStride + (size_t)(cb_) * cbStride;  \
    _Pragma("unroll")                                                           \
    for (int _g = 0; _g < 3; ++_g)                                              \
        bB[slot][_g] = *(const bf16x8*)(_wp + (size_t)_g * 512);                \
} while (0)

    LOADB(0, 0, 0);
    LOADB(1, 0, 1);

#pragma unroll
    for (int cb = 0; cb < 8; ++cb) {
        __syncthreads();                           // buf[cb&1] ready

        if (cb < 7) {                              // stage next cb, other buf
            const int nb = ((cb + 1) & 1) * HBYTES;
#pragma unroll
            for (int r = 0; r < 6; ++r)
                __builtin_amdgcn_global_load_lds(
                    (const __attribute__((address_space(1))) unsigned int*)
                        (xpb + (size_t)gpx[r] * 512 + (cb + 1) * 64 + q4),
                    (__attribute__((address_space(3))) unsigned int*)
                        &halo[nb + r * 4096 + t * 16],
                    16, 0, 0);
        }

#pragma unroll
        for (int kk = 0; kk < 9; ++kk) {
            // B prefetch distance 2, continuous across the cb seam
            if (kk < 7)       LOADB((kk + 2) % 3, cb, kk + 2);
            else if (cb < 7)  LOADB((kk + 2) % 3, cb + 1, kk - 7);

            const int dh = kk / 3 - 1;
            const int j  = kk % 3;                 // dw + 1
            const int IMM = (cb & 1) * HBYTES + (dh + 1) * 3584;  // compile-time
            bf16x8 aX[4];
#pragma unroll
            for (int f = 0; f < 4; ++f) {
                bf16x8 a = *(const bf16x8*)&halo[aB[f][j] + IMM];
                aX[f] = ((valMask[f] >> kk) & 1) ? a : zf;
            }
#pragma unroll
            for (int gg = 0; gg < 3; ++gg)
#pragma unroll
                for (int f = 0; f < 4; ++f)
                    acc[f][gg] = __builtin_amdgcn_mfma_f32_16x16x32_bf16(
                        aX[f], bB[kk % 3][gg], acc[f][gg], 0, 0, 0);
        }
    }
#undef LOADB

    // epilogue: D row (pixel) = (lane>>4)*4 + r, col (oc) = lane&15
#pragma unroll
    for (int f = 0; f < 4; ++f) {
        int p0 = pb + wv * 64 + f * 16 + laneq * 4;
        int img0 = p0 / HW_;
        int hw0 = p0 - img0 * HW_;
#pragma unroll
        for (int gg = 0; gg < 3; ++gg) {
            int oc = (fb + gg) * 16 + lane15;
            if (oc < oc_total) {
                float* op = out + ((size_t)img0 * oc_total + oc) * HW_ + hw0;
                *(f32x4*)op = acc[f][gg];
            }
        }
    }
}

extern "C" void kernel_launch(void* const* d_in, const int* in_sizes, int n_in,
                              void* d_out, int out_size, void* d_ws, size_t ws_size,
                              hipStream_t stream) {
    const float* x    = (const float*)d_in[0];
    const float* kern = (const float*)d_in[1];
    const float* ah   = (const float*)d_in[2];
    const float* bh   = (const float*)d_in[3];
    const int*   mode = (const int*)d_in[4];
    float* out = (float*)d_out;

    // oc is data-dependent but recoverable from out_size: oc*(16*3136+1)
    int oc_total = (out_size % (N_ * HW_ + 1) == 0) ? out_size / (N_ * HW_ + 1)
                                                    : OUTC;
    int nfTot = (oc_total + 15) / 16;
    int nby   = (nfTot + 2) / 3;             // 3 fragments (48 oc) per block
    int nfB   = nby * 3;

    // workspace layout. gparts (prep2h/vote lifetime) and wfrag (prep_w/conv
    // lifetime) are disjoint in time -> OVERLAY them to stay in the proven
    // ws envelope. Total: 25.7 + 4.0 MB + 2 KB.
    u16*   xp     = (u16*)d_ws;                                  // NPIX*C_ u16
    float* scratch = (float*)(xp + (size_t)NPIX * C_);
    float* gp     = scratch;                                     // 18*NPIX f32
    float* s2p    = scratch + (size_t)18 * NPIX;                 // 2*NPIX f32
    u16*   wfrag  = (u16*)scratch;                               // overlay
    int*   counts = (int*)(scratch + (size_t)20 * NPIX);         // 8
    int*   kbuck  = counts + 8;                                  // 512

    hipMemsetAsync(counts, 0, 8 * sizeof(int), stream);

    prep2h<<<NPB2, 128, 0, stream>>>(x, ah, xp, gp, s2p);
    vote_kernel<<<NVB + 128, 256, 0, stream>>>(gp, s2p, ah, bh, kern, counts,
                                               kbuck);
    prep_w<<<18 * nfB, 256, 0, stream>>>(kern, kbuck, counts, mode, out, wfrag,
                                         nfB, oc_total);
    conv_mfma<<<(NPIX / BLKPX) * nby, 256, 0, stream>>>(xp, wfrag, out, nfB,
                                                        oc_total, nby);
}